// Round 14
// baseline (378.339 us; speedup 1.0000x reference)
//
#include <hip/hip_runtime.h>
#include <stdint.h>

// B=4, T=4096, H=1024, K=256. BT = 16384, E = 2H = 2048.
// ws: w_in_bf @33554432 (4MB), w_out_bf @37748736 (4MB),
//     z @41943040 (64MB, (e,bt) bf16), cat @109051904 (64MB, (2e,bt)),
//     catT = z region (z dead after conv).

#define LDS_AS __attribute__((address_space(3)))
#define GLB_AS __attribute__((address_space(1)))

typedef __attribute__((ext_vector_type(8))) short bf16x8;
typedef __attribute__((ext_vector_type(4))) float f32x4;

__device__ __forceinline__ ushort f2bf(float f) {
  uint32_t u = __float_as_uint(f);
  u += 0x7fffu + ((u >> 16) & 1u);   // RNE
  return (ushort)(u >> 16);
}

// ---------------- cast fp32 -> bf16 (weights only now) ----------------
__global__ __launch_bounds__(256) void cast_kernel(const float* __restrict__ in,
                                                   ushort* __restrict__ out, int n4) {
  int i = blockIdx.x * 256 + threadIdx.x;
  if (i >= n4) return;
  float4 v = ((const float4*)in)[i];
  ushort4 o;
  o.x = f2bf(v.x); o.y = f2bf(v.y); o.z = f2bf(v.z); o.w = f2bf(v.w);
  ((ushort4*)out)[i] = o;
}

// ---------------- GEMM1: z(e,bt) = w_in(e,h) @ x(bt,h)^T, x read as FP32 --
// BM=128 (A, bf16), BN=256 (B = x, staged fp32, converted in-reg), BK=32.
// 2-deep (80KB -> 2 blocks/CU), 1-ahead, vmcnt(5). A-swizzle: r12 formulas
// (4-slot, key (row>>1)&3, measured 0 conflicts). B fp32 rows = 128B = 8
// slots, swizzle key row&7 (involution both sides, even 8-lane/slot spread).
__global__ __launch_bounds__(512, 4) void gemm1_xf32(const ushort* __restrict__ A,
                                                     const float* __restrict__ X,
                                                     const float* __restrict__ bias,
                                                     ushort* __restrict__ Z,
                                                     int M, int N, int Kd, int nbx) {
  // buffer d (d=0,1) at d*20480 ushorts: [A 4096][B fp32 16384]
  __shared__ __attribute__((aligned(16))) ushort lds[40960];   // 80 KB
  const int tid = threadIdx.x;
  const int lane = tid & 63, wid = tid >> 6;
  const int nwg = gridDim.x, bid = blockIdx.x;
  const int s = (bid & 7) * (nwg >> 3) + (bid >> 3);   // XCD swizzle
  const int m0 = (s % nbx) * 128, n0 = (s / nbx) * 256;  // m-inner
  const int wm = wid >> 2, wn = wid & 3;
  const int lr = lane & 15;
  // A staging (r12): 1 load/thread
  const int srowA = wid * 16 + (lane >> 2);
  const int scolA = ((lane & 3) ^ ((lane >> 3) & 3)) << 3;   // pre-swz ushort col
  const int rcA = (((lane >> 4) ^ ((lane >> 1) & 3)) << 3);  // swz read col

  f32x4 acc[4][4] = {};

  auto stageA = [&](int u) {
    const int boff = (u & 1) * 20480;
    const ushort* gp = A + (size_t)(m0 + srowA) * Kd + u * 32 + scolA;
    __builtin_amdgcn_global_load_lds((const GLB_AS void*)gp,
        (LDS_AS void*)(lds + boff + wid * 512), 16, 0, 0);
  };
  auto stageB = [&](int u) {   // 4 loads/thread: 256 rows x 32 fp32 (swizzled)
    const int boff = (u & 1) * 20480 + 4096;
#pragma unroll
    for (int l = 0; l < 4; ++l) {
      const int idx = l * 512 + tid;
      const int r = idx >> 3, sl = idx & 7;
      const float* gp = X + (size_t)(n0 + r) * Kd + u * 32 + ((sl ^ (r & 7)) << 2);
      __builtin_amdgcn_global_load_lds((const GLB_AS void*)gp,
          (LDS_AS void*)(lds + boff + (l * 512 + wid * 64) * 8), 16, 0, 0);
    }
  };

  stageA(0); stageB(0);

  const int NT = Kd >> 5;
  const int abase = (wm * 64 + lr) * 32 + rcA;
  const int g = lane >> 4;

  for (int u = 0; u < NT; ++u) {
    const int boff = (u & 1) * 20480;
    if (u + 1 < NT) {
      stageA(u + 1); stageB(u + 1);
      asm volatile("s_waitcnt vmcnt(5)" ::: "memory");   // stage(u) landed
    } else {
      asm volatile("s_waitcnt vmcnt(0)" ::: "memory");
    }
    __builtin_amdgcn_s_barrier();
    bf16x8 af[4], bfr[4];
#pragma unroll
    for (int mi = 0; mi < 4; ++mi)
      af[mi] = *(const bf16x8*)&lds[boff + abase + mi * 512];
#pragma unroll
    for (int ni = 0; ni < 4; ++ni) {
      const int r = wn * 64 + ni * 16 + lr;
      const int rb = boff + 4096 + r * 64;
      f32x4 lo = *(const f32x4*)&lds[rb + (((2 * g) ^ (r & 7)) << 3)];
      f32x4 hi = *(const f32x4*)&lds[rb + (((2 * g + 1) ^ (r & 7)) << 3)];
      bf16x8 v;
#pragma unroll
      for (int j = 0; j < 4; ++j) { v[j] = (short)f2bf(lo[j]); v[4 + j] = (short)f2bf(hi[j]); }
      bfr[ni] = v;
    }
    __builtin_amdgcn_s_setprio(1);
#pragma unroll
    for (int mi = 0; mi < 4; ++mi)
#pragma unroll
      for (int ni = 0; ni < 4; ++ni)
        acc[mi][ni] = __builtin_amdgcn_mfma_f32_16x16x32_bf16(af[mi], bfr[ni], acc[mi][ni], 0, 0, 0);
    __builtin_amdgcn_s_setprio(0);
    __builtin_amdgcn_s_barrier();
  }

  const int rj = (lane >> 4) << 2;
#pragma unroll
  for (int mi = 0; mi < 4; ++mi)
#pragma unroll
    for (int nf = 0; nf < 4; ++nf)
#pragma unroll
      for (int j = 0; j < 4; ++j) {
        int r = m0 + wm * 64 + mi * 16 + rj + j;
        int c = n0 + wn * 64 + nf * 16 + lr;
        Z[(size_t)r * N + c] = f2bf(acc[mi][nf][j] + bias[r]);
      }
}

// ---------------- GEMM2 (r9 best): C = A * Bt^T, bf16 ----------------
__global__ __launch_bounds__(512, 2) void gemm256(const ushort* __restrict__ A,
                                                  const ushort* __restrict__ Bt,
                                                  const float* __restrict__ bias,
                                                  float* __restrict__ Cout,
                                                  int M, int N, int Kd, int nbx) {
  __shared__ __attribute__((aligned(16))) ushort lds[65536];
  const int tid = threadIdx.x;
  const int lane = tid & 63, wid = tid >> 6;
  const int nwg = gridDim.x, bid = blockIdx.x;
  const int s = (bid & 7) * (nwg >> 3) + (bid >> 3);
  const int m0 = (s / nbx) * 256, n0 = (s % nbx) * 256;   // n-inner
  const int wm = wid >> 2, wn = wid & 3;
  const int lr = lane & 15;
  const int srow = wid * 16 + (lane >> 2);
  const int scol = ((lane & 3) ^ ((lane >> 3) & 3)) << 3;
  const int rc = (((lane >> 4) ^ ((lane >> 1) & 3)) << 3);

  f32x4 acc[8][4] = {};

  auto stageA = [&](int u) {
    const int boff = (u & 3) * 16384;
    const int kb = u * 32;
#pragma unroll
    for (int rr = 0; rr < 2; ++rr) {
      const ushort* gp = A + (size_t)(m0 + rr * 128 + srow) * Kd + kb + scol;
      __builtin_amdgcn_global_load_lds((const GLB_AS void*)gp,
          (LDS_AS void*)(lds + boff + rr * 4096 + wid * 512), 16, 0, 0);
    }
  };
  auto stageB = [&](int u) {
    const int boff = (u & 3) * 16384 + 8192;
    const int kb = u * 32;
#pragma unroll
    for (int rr = 0; rr < 2; ++rr) {
      const ushort* gp = Bt + (size_t)(n0 + rr * 128 + srow) * Kd + kb + scol;
      __builtin_amdgcn_global_load_lds((const GLB_AS void*)gp,
          (LDS_AS void*)(lds + boff + rr * 4096 + wid * 512), 16, 0, 0);
    }
  };

  stageA(0); stageB(0); stageA(1); stageB(1); stageA(2); stageB(2);
  asm volatile("s_waitcnt vmcnt(8)" ::: "memory");
  __builtin_amdgcn_s_barrier();

  const int NT = Kd >> 5;
  const int abase = (wm * 128 + lr) * 32 + rc;
  const int bbase = 8192 + (wn * 64 + lr) * 32 + rc;

  for (int u = 0; u < NT; ++u) {
    const int boff = (u & 3) * 16384;
    const bool st = (u + 3 < NT);
    bf16x8 af[8], bfr[4];
#pragma unroll
    for (int mi = 0; mi < 8; ++mi)
      af[mi] = *(const bf16x8*)&lds[boff + abase + mi * 512];
#pragma unroll
    for (int ni = 0; ni < 4; ++ni)
      bfr[ni] = *(const bf16x8*)&lds[boff + bbase + ni * 512];
    if (st) {
      stageA(u + 3); stageB(u + 3);
      asm volatile("s_waitcnt vmcnt(8)" ::: "memory");
    } else if (u + 2 < NT) {
      asm volatile("s_waitcnt vmcnt(4)" ::: "memory");
    } else if (u + 1 < NT) {
      asm volatile("s_waitcnt vmcnt(0)" ::: "memory");
    }
    __builtin_amdgcn_s_barrier();
    __builtin_amdgcn_s_setprio(1);
#pragma unroll
    for (int mi = 0; mi < 8; ++mi)
#pragma unroll
      for (int ni = 0; ni < 4; ++ni)
        acc[mi][ni] = __builtin_amdgcn_mfma_f32_16x16x32_bf16(af[mi], bfr[ni], acc[mi][ni], 0, 0, 0);
    __builtin_amdgcn_s_setprio(0);
  }

  const int rj = (lane >> 4) << 2;
#pragma unroll
  for (int mi = 0; mi < 8; ++mi)
#pragma unroll
    for (int nf = 0; nf < 4; ++nf)
#pragma unroll
      for (int j = 0; j < 4; ++j) {
        int r = m0 + wm * 128 + mi * 16 + rj + j;
        int c = n0 + wn * 64 + nf * 16 + lr;
        Cout[(size_t)r * N + c] = acc[mi][nf][j] + bias[c];
      }
}

// ---------------- causal depthwise conv + gating via MFMA (r11) ----------
__global__ __launch_bounds__(256) void conv_gate_mfma(
    const ushort* __restrict__ z, const float* __restrict__ w_a,
    const float* __restrict__ b_a, const float* __restrict__ w_b,
    const float* __restrict__ b_b, ushort* __restrict__ cat) {
  __shared__ __attribute__((aligned(16))) ushort za_s[4384];
  __shared__ __attribute__((aligned(16))) ushort zb_s[4384];
  __shared__ __attribute__((aligned(16))) ushort wxa_s[304];
  __shared__ __attribute__((aligned(16))) ushort wxb_s[304];
  const int c = blockIdx.x, b = blockIdx.y;
  const int tid = threadIdx.x, lane = tid & 63, wid = tid >> 6;
  const ushort* gza = z + (size_t)c * 16384 + b * 4096;
  const ushort* gzb = z + (size_t)(1024 + c) * 16384 + b * 4096;
#pragma unroll
  for (int it = 0; it < 2; ++it) {
    int s = wid + it * 4;
    __builtin_amdgcn_global_load_lds((const GLB_AS void*)(gza + s * 512 + lane * 8),
                                     (LDS_AS void*)(za_s + 288 + s * 512), 16, 0, 0);
    __builtin_amdgcn_global_load_lds((const GLB_AS void*)(gzb + s * 512 + lane * 8),
                                     (LDS_AS void*)(zb_s + 288 + s * 512), 16, 0, 0);
  }
  if (tid < 144) { ((uint*)za_s)[tid] = 0u; ((uint*)zb_s)[tid] = 0u; }
  wxa_s[15 + tid] = f2bf(w_a[c * 256 + 255 - tid]);
  wxb_s[15 + tid] = f2bf(w_b[c * 256 + 255 - tid]);
  if (tid < 15) { wxa_s[tid] = 0; wxb_s[tid] = 0; }
  if (tid < 33) { wxa_s[271 + tid] = 0; wxb_s[271 + tid] = 0; }
  __syncthreads();

  const int lidx = lane & 15, g = lane >> 4;
  bf16x8 afA[9], afB[9];
#pragma unroll
  for (int kb = 0; kb < 9; ++kb) {
    const int base = lidx + kb * 32 + 31 - 8 * g;
    bf16x8 a, bb;
#pragma unroll
    for (int jj = 0; jj < 8; ++jj) {
      a[jj]  = (short)wxa_s[base - jj];
      bb[jj] = (short)wxb_s[base - jj];
    }
    afA[kb] = a; afB[kb] = bb;
  }
  const float biasA = b_a[c], biasB = b_b[c];
  ushort* poA = cat + (size_t)c * 16384 + b * 4096;
  ushort* poB = cat + (size_t)(1024 + c) * 16384 + b * 4096;
#pragma unroll
  for (int cc = 0; cc < 4; ++cc) {
    const int T0 = (wid * 4 + cc) * 256;
    f32x4 accA = {}, accB = {};
#pragma unroll
    for (int kb = 0; kb < 9; ++kb) {
      const int idx = 272 + T0 + lidx * 16 - kb * 32 + g * 8;
      bf16x8 bza = *(const bf16x8*)&za_s[idx];
      bf16x8 bzb = *(const bf16x8*)&zb_s[idx];
      accA = __builtin_amdgcn_mfma_f32_16x16x32_bf16(afA[kb], bza, accA, 0, 0, 0);
      accB = __builtin_amdgcn_mfma_f32_16x16x32_bf16(afB[kb], bzb, accB, 0, 0, 0);
    }
    ushort4 oa, ob;
    const int t = T0 + lidx * 16 + g * 4;
#pragma unroll
    for (int j = 0; j < 4; ++j) {
      float ca = accA[j] + biasA, cb = accB[j] + biasB;
      float sa = 1.f / (1.f + __expf(-ca));
      float sb = 1.f / (1.f + __expf(-cb));
      float va = ca * sb, vb = cb * sa;
      if (j == 0) { oa.x = f2bf(va); ob.x = f2bf(vb); }
      if (j == 1) { oa.y = f2bf(va); ob.y = f2bf(vb); }
      if (j == 2) { oa.z = f2bf(va); ob.z = f2bf(vb); }
      if (j == 3) { oa.w = f2bf(va); ob.w = f2bf(vb); }
    }
    *(ushort4*)&poA[t] = oa;
    *(ushort4*)&poB[t] = ob;
  }
}

// ---------------- bf16 transpose: out(C,R) <- in(R,C) ----------------
__global__ __launch_bounds__(256) void transpose_bf16(const ushort* __restrict__ in,
                                                      ushort* __restrict__ out,
                                                      int R, int C) {
  __shared__ ushort tile[64][65];
  int c0 = blockIdx.x * 64, r0 = blockIdx.y * 64;
  int tc = threadIdx.x & 63, tr = threadIdx.x >> 6;
#pragma unroll
  for (int k = 0; k < 16; ++k) {
    int r = tr + k * 4;
    tile[r][tc] = in[(size_t)(r0 + r) * C + c0 + tc];
  }
  __syncthreads();
#pragma unroll
  for (int k = 0; k < 16; ++k) {
    int i = tr + k * 4;
    out[(size_t)(c0 + i) * R + r0 + tc] = tile[tc][i];
  }
}

extern "C" void kernel_launch(void* const* d_in, const int* in_sizes, int n_in,
                              void* d_out, int out_size, void* d_ws, size_t ws_size,
                              hipStream_t stream) {
  const float* x     = (const float*)d_in[0];
  const float* w_in  = (const float*)d_in[1];
  const float* b_in  = (const float*)d_in[2];
  const float* w_a   = (const float*)d_in[3];
  const float* b_a   = (const float*)d_in[4];
  const float* w_b   = (const float*)d_in[5];
  const float* b_b   = (const float*)d_in[6];
  const float* w_out = (const float*)d_in[7];
  const float* b_out = (const float*)d_in[8];

  uint8_t* ws = (uint8_t*)d_ws;
  ushort* w_in_bf  = (ushort*)(ws + 33554432);
  ushort* w_out_bf = (ushort*)(ws + 37748736);
  ushort* z        = (ushort*)(ws + 41943040);
  ushort* cat      = (ushort*)(ws + 109051904);
  ushort* catT     = z;  // reuse: z dead after conv

  cast_kernel<<<2048, 256, 0, stream>>>(w_in, w_in_bf, 524288);
  cast_kernel<<<2048, 256, 0, stream>>>(w_out, w_out_bf, 524288);

  // z(e,bt) = w_in(e,h) @ x(bt,h)^T + b_in[e], x consumed as fp32 directly.
  // 16 m-blocks (inner) x 64 n-blocks = 1024 wgs.
  gemm1_xf32<<<dim3(1024), 512, 0, stream>>>(w_in_bf, x, b_in, z,
                                             2048, 16384, 1024, 16);
  // conv + gate -> cat(2e, bt)
  conv_gate_mfma<<<dim3(1024, 4), 256, 0, stream>>>(z, w_a, b_a, w_b, b_b, cat);
  // catT(bt, 2e)
  transpose_bf16<<<dim3(256, 32), 256, 0, stream>>>(cat, catT, 2048, 16384);
  // out(bt,h) = catT(bt,2e) @ w_out(h,2e)^T + b_out[h]
  gemm256<<<dim3(256), 512, 0, stream>>>(catT, w_out_bf, b_out, (float*)d_out,
                                         16384, 1024, 2048, 4);
}

// Round 15
// 246.741 us; speedup vs baseline: 1.5333x; 1.5333x over previous
//
#include <hip/hip_runtime.h>
#include <stdint.h>

// B=4, T=4096, H=1024, K=256. BT = 16384, E = 2H = 2048.
// ws layout unchanged (168 MB).

#define LDS_AS __attribute__((address_space(3)))
#define GLB_AS __attribute__((address_space(1)))

typedef __attribute__((ext_vector_type(8))) short bf16x8;
typedef __attribute__((ext_vector_type(4))) float f32x4;

__device__ __forceinline__ ushort f2bf(float f) {
  uint32_t u = __float_as_uint(f);
  u += 0x7fffu + ((u >> 16) & 1u);   // RNE
  return (ushort)(u >> 16);
}

// ---------------- cast fp32 -> bf16, 4 elems/thread ----------------
__global__ __launch_bounds__(256) void cast_kernel(const float* __restrict__ in,
                                                   ushort* __restrict__ out, int n4) {
  int i = blockIdx.x * 256 + threadIdx.x;
  if (i >= n4) return;
  float4 v = ((const float4*)in)[i];
  ushort4 o;
  o.x = f2bf(v.x); o.y = f2bf(v.y); o.z = f2bf(v.z); o.w = f2bf(v.w);
  ((ushort4*)out)[i] = o;
}

// ---------------- GEMM 256x256, BK=32, 8 waves, FINE 2-phase/subtile ------
// Best measured GEMM (r11: 247.4us total). 4-deep subtile buffers, 3-ahead,
// XOR swizzle (0 conflicts), XCD grid swizzle, counted vmcnt per phase.
template <int MODE, int INNER_M>  // MODE 0: bf16 out+bias[row]; 1: f32 out+bias[col]
__global__ __launch_bounds__(512, 2) void gemm256(const ushort* __restrict__ A,
                                                  const ushort* __restrict__ Bt,
                                                  const float* __restrict__ bias,
                                                  void* __restrict__ Cout,
                                                  int M, int N, int Kd, int nbx) {
  __shared__ __attribute__((aligned(16))) ushort lds[65536];  // 4 x (A 16KB + B 16KB)
  const int tid = threadIdx.x;
  const int lane = tid & 63, wid = tid >> 6;
  const int nwg = gridDim.x, bid = blockIdx.x;
  const int s = (bid & 7) * (nwg >> 3) + (bid >> 3);   // XCD swizzle (nwg%8==0)
  const int m0 = (INNER_M ? (s % nbx) : (s / nbx)) * 256;
  const int n0 = (INNER_M ? (s / nbx) : (s % nbx)) * 256;
  const int wm = wid >> 2, wn = wid & 3;
  const int lr = lane & 15;
  const int srow = wid * 16 + (lane >> 2);                       // [0,128)
  const int scol = ((lane & 3) ^ ((lane >> 3) & 3)) << 3;        // pre-swz src
  const int rc = (((lane >> 4) ^ ((lane >> 1) & 3)) << 3);       // swz read col

  f32x4 acc[8][4] = {};

  auto stageA = [&](int u) {
    const int boff = (u & 3) * 16384;
    const int kb = u * 32;
#pragma unroll
    for (int rr = 0; rr < 2; ++rr) {
      const ushort* gp = A + (size_t)(m0 + rr * 128 + srow) * Kd + kb + scol;
      __builtin_amdgcn_global_load_lds((const GLB_AS void*)gp,
          (LDS_AS void*)(lds + boff + rr * 4096 + wid * 512), 16, 0, 0);
    }
  };
  auto stageB = [&](int u) {
    const int boff = (u & 3) * 16384 + 8192;
    const int kb = u * 32;
#pragma unroll
    for (int rr = 0; rr < 2; ++rr) {
      const ushort* gp = Bt + (size_t)(n0 + rr * 128 + srow) * Kd + kb + scol;
      __builtin_amdgcn_global_load_lds((const GLB_AS void*)gp,
          (LDS_AS void*)(lds + boff + rr * 4096 + wid * 512), 16, 0, 0);
    }
  };

  // prologue: stage subtiles 0,1,2 (12 loads); vmcnt(8) => subtile 0 landed
  stageA(0); stageB(0); stageA(1); stageB(1); stageA(2); stageB(2);
  asm volatile("s_waitcnt vmcnt(8)" ::: "memory");
  __builtin_amdgcn_s_barrier();

  const int NT = Kd >> 5;
  const int abase = (wm * 128 + lr) * 32 + rc;
  const int bbase = 8192 + (wn * 64 + lr) * 32 + rc;

  for (int u = 0; u < NT; ++u) {
    const int boff = (u & 3) * 16384;
    const bool st = (u + 3 < NT);
    bf16x8 af[8], bfr[4];
    // ---------- phase 0: read A(8)+B01(2), stage A(u+3), MFMA ni{0,1} -----
#pragma unroll
    for (int mi = 0; mi < 8; ++mi)
      af[mi] = *(const bf16x8*)&lds[boff + abase + mi * 512];
    bfr[0] = *(const bf16x8*)&lds[boff + bbase];
    bfr[1] = *(const bf16x8*)&lds[boff + bbase + 512];
    if (st)                { stageA(u + 3);
                             asm volatile("s_waitcnt vmcnt(10)" ::: "memory"); }
    else if (u + 3 == NT)  { asm volatile("s_waitcnt vmcnt(8)" ::: "memory"); }
    else if (u + 2 == NT)  { asm volatile("s_waitcnt vmcnt(4)" ::: "memory"); }
    else                   { asm volatile("s_waitcnt vmcnt(0)" ::: "memory"); }
    __builtin_amdgcn_s_barrier();
    __builtin_amdgcn_s_setprio(1);
#pragma unroll
    for (int mi = 0; mi < 8; ++mi) {
      acc[mi][0] = __builtin_amdgcn_mfma_f32_16x16x32_bf16(af[mi], bfr[0], acc[mi][0], 0, 0, 0);
      acc[mi][1] = __builtin_amdgcn_mfma_f32_16x16x32_bf16(af[mi], bfr[1], acc[mi][1], 0, 0, 0);
    }
    __builtin_amdgcn_s_setprio(0);
    // ---------- phase 1: read B23(2), stage B(u+3), MFMA ni{2,3} ----------
    bfr[2] = *(const bf16x8*)&lds[boff + bbase + 1024];
    bfr[3] = *(const bf16x8*)&lds[boff + bbase + 1536];
    if (st)                { stageB(u + 3);
                             asm volatile("s_waitcnt vmcnt(12)" ::: "memory"); }
    else if (u + 3 == NT)  { asm volatile("s_waitcnt vmcnt(8)" ::: "memory"); }
    else if (u + 2 == NT)  { asm volatile("s_waitcnt vmcnt(4)" ::: "memory"); }
    __builtin_amdgcn_s_barrier();
    __builtin_amdgcn_s_setprio(1);
#pragma unroll
    for (int mi = 0; mi < 8; ++mi) {
      acc[mi][2] = __builtin_amdgcn_mfma_f32_16x16x32_bf16(af[mi], bfr[2], acc[mi][2], 0, 0, 0);
      acc[mi][3] = __builtin_amdgcn_mfma_f32_16x16x32_bf16(af[mi], bfr[3], acc[mi][3], 0, 0, 0);
    }
    __builtin_amdgcn_s_setprio(0);
  }

  // epilogue
  const int rj = (lane >> 4) << 2;
#pragma unroll
  for (int mi = 0; mi < 8; ++mi)
#pragma unroll
    for (int nf = 0; nf < 4; ++nf)
#pragma unroll
      for (int j = 0; j < 4; ++j) {
        int r = m0 + wm * 128 + mi * 16 + rj + j;
        int c = n0 + wn * 64 + nf * 16 + lr;
        float v = acc[mi][nf][j];
        if (MODE == 0) {
          v += bias[r];
          ((ushort*)Cout)[(size_t)r * N + c] = f2bf(v);
        } else {
          v += bias[c];
          ((float*)Cout)[(size_t)r * N + c] = v;
        }
      }
}

// ---------------- causal depthwise conv + gating via MFMA ----------------
// y[t] = sum_j w[255-j] z[t-j] (cross-correlation). wx[i]=w[255-(i-15)],
// support [15,270]. A'_kb[m,kk]=wx[m+32kb+31-kk]; B'_kb[kk,n]=zs[272+T0+16n-32kb+kk].
__global__ __launch_bounds__(256) void conv_gate_mfma(
    const ushort* __restrict__ z, const float* __restrict__ w_a,
    const float* __restrict__ b_a, const float* __restrict__ w_b,
    const float* __restrict__ b_b, ushort* __restrict__ cat) {
  __shared__ __attribute__((aligned(16))) ushort za_s[4384];
  __shared__ __attribute__((aligned(16))) ushort zb_s[4384];
  __shared__ __attribute__((aligned(16))) ushort wxa_s[304];
  __shared__ __attribute__((aligned(16))) ushort wxb_s[304];
  const int c = blockIdx.x, b = blockIdx.y;
  const int tid = threadIdx.x, lane = tid & 63, wid = tid >> 6;
  const ushort* gza = z + (size_t)c * 16384 + b * 4096;
  const ushort* gzb = z + (size_t)(1024 + c) * 16384 + b * 4096;
#pragma unroll
  for (int it = 0; it < 2; ++it) {
    int s = wid + it * 4;
    __builtin_amdgcn_global_load_lds((const GLB_AS void*)(gza + s * 512 + lane * 8),
                                     (LDS_AS void*)(za_s + 288 + s * 512), 16, 0, 0);
    __builtin_amdgcn_global_load_lds((const GLB_AS void*)(gzb + s * 512 + lane * 8),
                                     (LDS_AS void*)(zb_s + 288 + s * 512), 16, 0, 0);
  }
  if (tid < 144) { ((uint*)za_s)[tid] = 0u; ((uint*)zb_s)[tid] = 0u; }
  wxa_s[15 + tid] = f2bf(w_a[c * 256 + 255 - tid]);
  wxb_s[15 + tid] = f2bf(w_b[c * 256 + 255 - tid]);
  if (tid < 15) { wxa_s[tid] = 0; wxb_s[tid] = 0; }
  if (tid < 33) { wxa_s[271 + tid] = 0; wxb_s[271 + tid] = 0; }
  __syncthreads();

  const int lidx = lane & 15, g = lane >> 4;
  bf16x8 afA[9], afB[9];
#pragma unroll
  for (int kb = 0; kb < 9; ++kb) {
    const int base = lidx + kb * 32 + 31 - 8 * g;
    bf16x8 a, bb;
#pragma unroll
    for (int jj = 0; jj < 8; ++jj) {
      a[jj]  = (short)wxa_s[base - jj];
      bb[jj] = (short)wxb_s[base - jj];
    }
    afA[kb] = a; afB[kb] = bb;
  }
  const float biasA = b_a[c], biasB = b_b[c];
  ushort* poA = cat + (size_t)c * 16384 + b * 4096;
  ushort* poB = cat + (size_t)(1024 + c) * 16384 + b * 4096;
#pragma unroll
  for (int cc = 0; cc < 4; ++cc) {
    const int T0 = (wid * 4 + cc) * 256;
    f32x4 accA = {}, accB = {};
#pragma unroll
    for (int kb = 0; kb < 9; ++kb) {
      const int idx = 272 + T0 + lidx * 16 - kb * 32 + g * 8;
      bf16x8 bza = *(const bf16x8*)&za_s[idx];
      bf16x8 bzb = *(const bf16x8*)&zb_s[idx];
      accA = __builtin_amdgcn_mfma_f32_16x16x32_bf16(afA[kb], bza, accA, 0, 0, 0);
      accB = __builtin_amdgcn_mfma_f32_16x16x32_bf16(afB[kb], bzb, accB, 0, 0, 0);
    }
    ushort4 oa, ob;
    const int t = T0 + lidx * 16 + g * 4;
#pragma unroll
    for (int j = 0; j < 4; ++j) {
      float ca = accA[j] + biasA, cb = accB[j] + biasB;
      float sa = 1.f / (1.f + __expf(-ca));
      float sb = 1.f / (1.f + __expf(-cb));
      float va = ca * sb, vb = cb * sa;
      if (j == 0) { oa.x = f2bf(va); ob.x = f2bf(vb); }
      if (j == 1) { oa.y = f2bf(va); ob.y = f2bf(vb); }
      if (j == 2) { oa.z = f2bf(va); ob.z = f2bf(vb); }
      if (j == 3) { oa.w = f2bf(va); ob.w = f2bf(vb); }
    }
    *(ushort4*)&poA[t] = oa;
    *(ushort4*)&poB[t] = ob;
  }
}

// ---------------- bf16 transpose: out(C,R) <- in(R,C) ----------------
__global__ __launch_bounds__(256) void transpose_bf16(const ushort* __restrict__ in,
                                                      ushort* __restrict__ out,
                                                      int R, int C) {
  __shared__ ushort tile[64][65];
  int c0 = blockIdx.x * 64, r0 = blockIdx.y * 64;
  int tc = threadIdx.x & 63, tr = threadIdx.x >> 6;
#pragma unroll
  for (int k = 0; k < 16; ++k) {
    int r = tr + k * 4;
    tile[r][tc] = in[(size_t)(r0 + r) * C + c0 + tc];
  }
  __syncthreads();
#pragma unroll
  for (int k = 0; k < 16; ++k) {
    int i = tr + k * 4;
    out[(size_t)(c0 + i) * R + r0 + tc] = tile[tc][i];
  }
}

extern "C" void kernel_launch(void* const* d_in, const int* in_sizes, int n_in,
                              void* d_out, int out_size, void* d_ws, size_t ws_size,
                              hipStream_t stream) {
  const float* x     = (const float*)d_in[0];
  const float* w_in  = (const float*)d_in[1];
  const float* b_in  = (const float*)d_in[2];
  const float* w_a   = (const float*)d_in[3];
  const float* b_a   = (const float*)d_in[4];
  const float* w_b   = (const float*)d_in[5];
  const float* b_b   = (const float*)d_in[6];
  const float* w_out = (const float*)d_in[7];
  const float* b_out = (const float*)d_in[8];

  uint8_t* ws = (uint8_t*)d_ws;
  ushort* x_bf     = (ushort*)(ws);
  ushort* w_in_bf  = (ushort*)(ws + 33554432);
  ushort* w_out_bf = (ushort*)(ws + 37748736);
  ushort* z        = (ushort*)(ws + 41943040);
  ushort* cat      = (ushort*)(ws + 109051904);
  ushort* catT     = z;  // reuse: z dead after conv

  cast_kernel<<<16384, 256, 0, stream>>>(x, x_bf, 4194304);
  cast_kernel<<<2048, 256, 0, stream>>>(w_in, w_in_bf, 524288);
  cast_kernel<<<2048, 256, 0, stream>>>(w_out, w_out_bf, 524288);

  // z(e,bt) = w_in(e,h) @ x(bt,h)^T + b_in[e]   M=2048,N=16384,K=1024
  gemm256<0, 1><<<dim3(512), 512, 0, stream>>>(w_in_bf, x_bf, b_in, z,
                                               2048, 16384, 1024, 8);
  // conv + gate -> cat(2e, bt)
  conv_gate_mfma<<<dim3(1024, 4), 256, 0, stream>>>(z, w_a, b_a, w_b, b_b, cat);
  // catT(bt, 2e)
  transpose_bf16<<<dim3(256, 32), 256, 0, stream>>>(cat, catT, 2048, 16384);
  // out(bt,h) = catT(bt,2e) @ w_out(h,2e)^T + b_out[h]  M=16384,N=1024,K=2048
  gemm256<1, 0><<<dim3(256), 512, 0, stream>>>(catT, w_out_bf, b_out, d_out,
                                               16384, 1024, 2048, 4);
}